// Round 5
// baseline (397.778 us; speedup 1.0000x reference)
//
#include <hip/hip_runtime.h>

// StatefulRecurrent: s_t = A*s_{t-1} + x_t (complex diagonal A), out = [Re(s),Im(s)].
// B=16, T=4096, D=512. SINGLE fused kernel, block-local chunked scan:
//   - Block owns (b, 32-d slice) x all T. 1024 threads = 64 segments x 16 d-pairs.
//   - Phase 1: each thread scans its 64-step segment (zero-init). Normal x loads.
//   - __syncthreads (only barrier; scan dependency is intra-block).
//   - Phase 2: incoming state by serial rescan of LDS aggregates (S = A^64*S + agg_j).
//   - Phase 3: replay re-reading x (L3 hit hopefully), NORMAL float4 stores.
//
// ROUND-5 EXPERIMENT (single variable vs round 4): out stores nt -> NORMAL.
// Rationale: rounds 1/3/4 (three different structures) all pinned at ~165-172 us
// kernel time; 268 MB / 165 us = 1.6 TB/s = suspected nt-store slow path. The
// harness fill kernel proves NORMAL full-line stores run at 6.5 TB/s at 10% occ.
// If this lands ~300-325 us total, nt stores were the wall; if ~flat, nt is
// exonerated and the limiter is elsewhere.

#define B_  16
#define T_  4096
#define D_  512
#define SEG 64
#define NS  (T_ / SEG)   // 64 segments
#define NDP 16           // d-pairs per block (32 consecutive d)

typedef float v2f __attribute__((ext_vector_type(2)));
typedef float v4f __attribute__((ext_vector_type(4)));

__global__ __launch_bounds__(1024) void fused_scan_kernel(
    const float* __restrict__ x,
    const float* __restrict__ Ar_g, const float* __restrict__ Ai_g,
    v4f* __restrict__ out4) {
  int tid  = threadIdx.x;
  int dp   = tid & (NDP - 1);   // d-pair within block: 16 contiguous d-pairs
  int seg  = tid >> 4;          // 0..63
  int n    = blockIdx.x;
  int dblk = n & 15;
  int b    = n >> 4;
  int d    = dblk * (2 * NDP) + dp * 2;
  int t0   = seg * SEG;

  __shared__ v4f agg[NS][NDP];  // 16 KB

  float2 Ar = *(const float2*)(Ar_g + d);
  float2 Ai = *(const float2*)(Ai_g + d);

  // ---- Phase 1: local zero-init scan; NORMAL loads warm L3 with x ----
  const v2f* xp = (const v2f*)(x + ((size_t)(b * T_ + t0)) * D_ + d);
  float s0r = 0.f, s0i = 0.f, s1r = 0.f, s1i = 0.f;
#pragma unroll 8
  for (int k = 0; k < SEG; ++k) {
    v2f xv = xp[(size_t)k * (D_ / 2)];
    float n0r = fmaf(s0r, Ar.x, fmaf(-s0i, Ai.x, xv.x));
    float n0i = fmaf(s0r, Ai.x, s0i * Ar.x);
    float n1r = fmaf(s1r, Ar.y, fmaf(-s1i, Ai.y, xv.y));
    float n1i = fmaf(s1r, Ai.y, s1i * Ar.y);
    s0r = n0r; s0i = n0i; s1r = n1r; s1i = n1i;
  }
  agg[seg][dp] = (v4f){s0r, s0i, s1r, s1i};
  __syncthreads();

  // ---- A^64 per d-component by 6 squarings ----
  float p0r = Ar.x, p0i = Ai.x, p1r = Ar.y, p1i = Ai.y;
#pragma unroll
  for (int q = 0; q < 6; ++q) {
    float t0r = p0r * p0r - p0i * p0i; float t0i = 2.f * p0r * p0i;
    float t1r = p1r * p1r - p1i * p1i; float t1i = 2.f * p1r * p1i;
    p0r = t0r; p0i = t0i; p1r = t1r; p1i = t1i;
  }

  // ---- Phase 2: incoming state S = sum_{j<seg} A^{64(seg-1-j)} agg_j (LDS rescan) ----
  float S0r = 0.f, S0i = 0.f, S1r = 0.f, S1i = 0.f;
  for (int j = 0; j < seg; ++j) {
    v4f g = agg[j][dp];
    float n0r = fmaf(p0r, S0r, fmaf(-p0i, S0i, g.x));
    float n0i = fmaf(p0i, S0r, fmaf(p0r, S0i, g.y));
    float n1r = fmaf(p1r, S1r, fmaf(-p1i, S1i, g.z));
    float n1i = fmaf(p1i, S1r, fmaf(p1r, S1i, g.w));
    S0r = n0r; S0i = n0i; S1r = n1r; S1i = n1i;
  }

  // ---- Phase 3: replay from incoming state, re-reading x; NORMAL stores ----
  // out4 index: ((b*T+t)*D + d)*2 floats / 4 = (b*T+t)*(D/2) + d/2
  v4f* op = out4 + ((size_t)(b * T_ + t0)) * (D_ / 2) + (d >> 1);
#pragma unroll 8
  for (int k = 0; k < SEG; ++k) {
    v2f xv = xp[(size_t)k * (D_ / 2)];
    float n0r = fmaf(S0r, Ar.x, fmaf(-S0i, Ai.x, xv.x));
    float n0i = fmaf(S0r, Ai.x, S0i * Ar.x);
    float n1r = fmaf(S1r, Ar.y, fmaf(-S1i, Ai.y, xv.y));
    float n1i = fmaf(S1r, Ai.y, S1i * Ar.y);
    S0r = n0r; S0i = n0i; S1r = n1r; S1i = n1i;
    op[(size_t)k * (D_ / 2)] = (v4f){S0r, S0i, S1r, S1i};
  }
}

extern "C" void kernel_launch(void* const* d_in, const int* in_sizes, int n_in,
                              void* d_out, int out_size, void* d_ws, size_t ws_size,
                              hipStream_t stream) {
  const float* x  = (const float*)d_in[0];
  const float* Ar = (const float*)d_in[1];
  const float* Ai = (const float*)d_in[2];
  v4f* out = (v4f*)d_out;

  // 16 b x 16 d-blocks = 256 blocks x 1024 threads (1 block/CU, 16 waves/CU)
  fused_scan_kernel<<<dim3(256), dim3(1024), 0, stream>>>(x, Ar, Ai, out);
}

// Round 6
// 381.035 us; speedup vs baseline: 1.0439x; 1.0439x over previous
//
#include <hip/hip_runtime.h>

// StatefulRecurrent: s_t = A*s_{t-1} + x_t (complex diagonal A), out = [Re(s),Im(s)].
// B=16, T=4096, D=512. Two-pass chunked scan, FULL-D BLOCKS for sequential footprint:
//
// Round-6 theory: all prior variants wrote out at ~1.6-1.8 TB/s because d-sliced
// blocks scatter sub-KB chunks (4-KB stride) across the whole 268 MB surface ->
// DRAM page thrash. Fill kernel (sequential sweep) proves 6.5 TB/s. This version:
// block = (b, segment) owns ALL 512 d -> reads a solid 128 KB of x, writes a solid
// 256 KB of out, row-by-row. 256 concurrent blocks = 256 sequential streams.
//
//   K1: block (b,seg): per-thread (d-pair) zero-init scan of 64 steps; aggregate
//       -> buf[seg][b][d] (4 KB contiguous per block; 4 MB total, L2/L3-resident).
//   K2: same geometry; A^64 by 6 squarings; incoming state by rescan of buf
//       (S = A^64*S + agg_j, j<seg); replay segment re-reading x (L3-warm from K1),
//       nt-store full 4-KB rows (wave-instr = 1 KB contiguous, block = 256 KB solid).

#define B_  16
#define T_  4096
#define D_  512
#define SEG 64
#define NS  (T_ / SEG)     // 64 segments
#define BD  (B_ * D_)      // float2 entries per segment in buf (one per d)

typedef float v2f __attribute__((ext_vector_type(2)));
typedef float v4f __attribute__((ext_vector_type(4)));

__global__ __launch_bounds__(256) void seg_agg_kernel(
    const float* __restrict__ x,
    const float* __restrict__ Ar_g, const float* __restrict__ Ai_g,
    float2* __restrict__ buf) {
  int t   = threadIdx.x;        // 0..255 -> d-pair
  int n   = blockIdx.x;
  int seg = n & 63;             // consecutive blocks = consecutive segments (sweep order)
  int b   = n >> 6;
  int d   = t * 2;
  int t0  = seg * SEG;

  float2 Ar = *(const float2*)(Ar_g + d);
  float2 Ai = *(const float2*)(Ai_g + d);
  float s0r = 0.f, s0i = 0.f, s1r = 0.f, s1i = 0.f;
  // Normal loads: sequential 128-KB block region; warms L3 for K2's re-read.
  const v2f* xp = (const v2f*)(x + ((size_t)(b * T_ + t0)) * D_ + d);
#pragma unroll 8
  for (int k = 0; k < SEG; ++k) {
    v2f xv = xp[(size_t)k * (D_ / 2)];
    float n0r = fmaf(s0r, Ar.x, fmaf(-s0i, Ai.x, xv.x));
    float n0i = fmaf(s0r, Ai.x, s0i * Ar.x);
    float n1r = fmaf(s1r, Ar.y, fmaf(-s1i, Ai.y, xv.y));
    float n1i = fmaf(s1r, Ai.y, s1i * Ar.y);
    s0r = n0r; s0i = n0i; s1r = n1r; s1i = n1i;
  }
  // buf entry = one float2 per d; block writes 256 consecutive float4 = 4 KB.
  *(float4*)(buf + (size_t)seg * BD + b * D_ + d) = make_float4(s0r, s0i, s1r, s1i);
}

__global__ __launch_bounds__(256) void apply_kernel(
    const float* __restrict__ x,
    const float* __restrict__ Ar_g, const float* __restrict__ Ai_g,
    const float2* __restrict__ buf,
    v4f* __restrict__ out4) {
  int t   = threadIdx.x;
  int n   = blockIdx.x;
  int seg = n & 63;
  int b   = n >> 6;
  int d   = t * 2;
  int t0  = seg * SEG;

  float2 Ar = *(const float2*)(Ar_g + d);
  float2 Ai = *(const float2*)(Ai_g + d);

  // A^64 per d-component by 6 squarings
  float p0r = Ar.x, p0i = Ai.x, p1r = Ar.y, p1i = Ai.y;
#pragma unroll
  for (int q = 0; q < 6; ++q) {
    float t0r = p0r * p0r - p0i * p0i; float t0i = 2.f * p0r * p0i;
    float t1r = p1r * p1r - p1i * p1i; float t1i = 2.f * p1r * p1i;
    p0r = t0r; p0i = t0i; p1r = t1r; p1i = t1i;
  }

  // Incoming state: S = sum_{j<seg} A^{64(seg-1-j)} agg_j, via S = A64*S + agg_j.
  // buf is 4 MB -> L2/L3-resident; lanes read 1 KB contiguous per instruction.
  float S0r = 0.f, S0i = 0.f, S1r = 0.f, S1i = 0.f;
  const float* bbase = (const float*)(buf + b * D_ + d);
#pragma unroll 8
  for (int j = 0; j < seg; ++j) {
    float4 gv = *(const float4*)(bbase + (size_t)j * (BD * 2));
    float n0r = fmaf(p0r, S0r, fmaf(-p0i, S0i, gv.x));
    float n0i = fmaf(p0i, S0r, fmaf(p0r, S0i, gv.y));
    float n1r = fmaf(p1r, S1r, fmaf(-p1i, S1i, gv.z));
    float n1i = fmaf(p1i, S1r, fmaf(p1r, S1i, gv.w));
    S0r = n0r; S0i = n0i; S1r = n1r; S1i = n1i;
  }

  // Replay: re-read x (L3-warm, sequential), nt-store out.
  // Wave instr = 64 consecutive v4f = 1 KB; block sweeps 256 KB solid.
  const v2f* xp = (const v2f*)(x + ((size_t)(b * T_ + t0)) * D_ + d);
  v4f* op = out4 + ((size_t)(b * T_ + t0)) * (D_ / 2) + t;
#pragma unroll 8
  for (int k = 0; k < SEG; ++k) {
    v2f xv = xp[(size_t)k * (D_ / 2)];
    float n0r = fmaf(S0r, Ar.x, fmaf(-S0i, Ai.x, xv.x));
    float n0i = fmaf(S0r, Ai.x, S0i * Ar.x);
    float n1r = fmaf(S1r, Ar.y, fmaf(-S1i, Ai.y, xv.y));
    float n1i = fmaf(S1r, Ai.y, S1i * Ar.y);
    S0r = n0r; S0i = n0i; S1r = n1r; S1i = n1i;
    v4f ov = {S0r, S0i, S1r, S1i};
    __builtin_nontemporal_store(ov, op + (size_t)k * (D_ / 2));
  }
}

extern "C" void kernel_launch(void* const* d_in, const int* in_sizes, int n_in,
                              void* d_out, int out_size, void* d_ws, size_t ws_size,
                              hipStream_t stream) {
  const float* x  = (const float*)d_in[0];
  const float* Ar = (const float*)d_in[1];
  const float* Ai = (const float*)d_in[2];
  v4f* out = (v4f*)d_out;
  float2* buf = (float2*)d_ws;  // NS*BD float2 = 4 MB scratch

  // 1024 blocks (b x seg) x 256 threads = 16 waves/CU
  seg_agg_kernel<<<dim3(1024), dim3(256), 0, stream>>>(x, Ar, Ai, buf);
  apply_kernel<<<dim3(1024), dim3(256), 0, stream>>>(x, Ar, Ai, buf, out);
}